// Round 1
// baseline (190.209 us; speedup 1.0000x reference)
//
#include <hip/hip_runtime.h>
#include <math.h>

#define B_SZ 1024
#define E_SZ 512
#define C_SZ 16384
#define MRG 0.1f
#define ALPHA 32.0f
#define K_HY 1.0f
#define LAM 0.1f

typedef __bf16 bf16;
typedef bf16 bf16x8 __attribute__((ext_vector_type(8)));
typedef float f32x4 __attribute__((ext_vector_type(4)));

__device__ __forceinline__ void async16(const void* g, void* l) {
    __builtin_amdgcn_global_load_lds(
        (const __attribute__((address_space(1))) void*)g,
        (__attribute__((address_space(3))) void*)l,
        16, 0, 0);
}

// ---------------- per-class scalars: outlierSim, invEff ----------------
__global__ void class_scalars(const float* __restrict__ effNum,
                              const float* __restrict__ lSim,
                              float* __restrict__ oSim,
                              float* __restrict__ iEff) {
    int c = blockIdx.x * 256 + threadIdx.x;
    if (c < C_SZ) {
        float en = effNum[c], ls = lSim[c];
        float wb = 1.0f / (1.0f + log1pf(en));
        float eta = (1.0f + K_HY * (1.0f - ls)) * wb + LAM;
        oSim[c] = ls - eta;
        iEff[c] = 1.0f / fmaxf(1.0f, en);
    }
}

// ---------------- proxy row-l2norm -> bf16 (one wave per row) ----------------
__global__ void proxy_norm(const float* __restrict__ proxies, bf16* __restrict__ Pbf) {
    int row = (blockIdx.x * 256 + threadIdx.x) >> 6;
    int lane = threadIdx.x & 63;
    const float* pr = proxies + (size_t)row * E_SZ + lane * 8;
    float4 v0 = *(const float4*)pr;
    float4 v1 = *(const float4*)(pr + 4);
    float ss = v0.x * v0.x + v0.y * v0.y + v0.z * v0.z + v0.w * v0.w +
               v1.x * v1.x + v1.y * v1.y + v1.z * v1.z + v1.w * v1.w;
#pragma unroll
    for (int m = 1; m < 64; m <<= 1) ss += __shfl_xor(ss, m);
    float inv = 1.0f / sqrtf(ss + 1e-12f);
    bf16x8 o;
    o[0] = (bf16)(v0.x * inv); o[1] = (bf16)(v0.y * inv);
    o[2] = (bf16)(v0.z * inv); o[3] = (bf16)(v0.w * inv);
    o[4] = (bf16)(v1.x * inv); o[5] = (bf16)(v1.y * inv);
    o[6] = (bf16)(v1.z * inv); o[7] = (bf16)(v1.w * inv);
    *(bf16x8*)(Pbf + (size_t)row * E_SZ + lane * 8) = o;
}

// ---------------- inputs -> bf16 ----------------
__global__ void convert_inputs(const float* __restrict__ x, bf16* __restrict__ y) {
    int i = (blockIdx.x * 256 + threadIdx.x) * 8;
    float4 v0 = *(const float4*)(x + i);
    float4 v1 = *(const float4*)(x + i + 4);
    bf16x8 o;
    o[0] = (bf16)v0.x; o[1] = (bf16)v0.y; o[2] = (bf16)v0.z; o[3] = (bf16)v0.w;
    o[4] = (bf16)v1.x; o[5] = (bf16)v1.y; o[6] = (bf16)v1.z; o[7] = (bf16)v1.w;
    *(bf16x8*)(y + i) = o;
}

// ---------------- class counts ----------------
__global__ void count_targets(const int* __restrict__ tg, int* __restrict__ cnt) {
    int i = blockIdx.x * 256 + threadIdx.x;
    if (i < B_SZ) atomicAdd(&cnt[tg[i]], 1);
}

// ---------------- fused GEMM (bf16 MFMA) + epilogue ----------------
// Tile: BM=128 (batch rows), BN=128 (classes), BK=32. 4 waves, each 64x64.
__global__ __launch_bounds__(256) void gemm_epilogue(
    const bf16* __restrict__ Abf,   // [B][E]
    const bf16* __restrict__ Pbf,   // [C][E] normalized
    const int* __restrict__ targets,
    const float* __restrict__ oSimA,
    const float* __restrict__ iEffA,
    float* __restrict__ posExp,
    float* __restrict__ negExp,
    float* __restrict__ negVals) {
    __shared__ __align__(16) bf16 Alds[128 * 32];
    __shared__ __align__(16) bf16 Blds[128 * 32];
    __shared__ int tgtLds[128];

    const int tid = threadIdx.x;
    const int wave = tid >> 6, lane = tid & 63;
    const int quad = lane >> 4, l16 = lane & 15;
    const int wRow = (wave >> 1) * 64, wCol = (wave & 1) * 64;
    const int bn0 = blockIdx.x * 128, bm0 = blockIdx.y * 128;

    if (tid < 128) tgtLds[tid] = targets[bm0 + tid];

    f32x4 zero = {0.f, 0.f, 0.f, 0.f};
    f32x4 acc[4][4];
#pragma unroll
    for (int i = 0; i < 4; ++i)
#pragma unroll
        for (int j = 0; j < 4; ++j) acc[i][j] = zero;

    const int ldRow = lane >> 2;      // 0..15 row within 16-row chunk
    const int ldK = (lane & 3) * 8;   // bf16 element offset within BK

    const bf16* gA = Abf + (size_t)(bm0 + wave * 32 + ldRow) * E_SZ + ldK;
    const bf16* gB = Pbf + (size_t)(bn0 + wave * 32 + ldRow) * E_SZ + ldK;

    for (int k0 = 0; k0 < E_SZ; k0 += 32) {
        __syncthreads();
#pragma unroll
        for (int j = 0; j < 2; ++j) {
            int chunk = wave * 2 + j;
            async16(gA + (size_t)j * 16 * E_SZ + k0, &Alds[chunk * 512]);
            async16(gB + (size_t)j * 16 * E_SZ + k0, &Blds[chunk * 512]);
        }
        __syncthreads();
        bf16x8 af[4], bff[4];
#pragma unroll
        for (int mi = 0; mi < 4; ++mi)
            af[mi] = *(const bf16x8*)&Alds[(wRow + mi * 16 + l16) * 32 + quad * 8];
#pragma unroll
        for (int ni = 0; ni < 4; ++ni)
            bff[ni] = *(const bf16x8*)&Blds[(wCol + ni * 16 + l16) * 32 + quad * 8];
#pragma unroll
        for (int mi = 0; mi < 4; ++mi)
#pragma unroll
            for (int ni = 0; ni < 4; ++ni)
                acc[mi][ni] = __builtin_amdgcn_mfma_f32_16x16x32_bf16(
                    af[mi], bff[ni], acc[mi][ni], 0, 0, 0);
    }

    // -------- epilogue: per-class (column) reductions --------
    int colG[4];
    float oS[4], iE[4];
#pragma unroll
    for (int ni = 0; ni < 4; ++ni) {
        colG[ni] = bn0 + wCol + ni * 16 + l16;
        oS[ni] = oSimA[colG[ni]];
        iE[ni] = iEffA[colG[ni]];
    }
    float negE[4] = {0.f, 0.f, 0.f, 0.f};
    float negV[4] = {0.f, 0.f, 0.f, 0.f};
#pragma unroll
    for (int mi = 0; mi < 4; ++mi) {
#pragma unroll
        for (int r = 0; r < 4; ++r) {
            int rowL = wRow + mi * 16 + quad * 4 + r;
            int tgt = tgtLds[rowL];
#pragma unroll
            for (int ni = 0; ni < 4; ++ni) {
                float cosv = acc[mi][ni][r];
                if (tgt == colG[ni]) {
                    // positive position: mask = 1
                    atomicAdd(&posExp[colG[ni]], expf(ALPHA * (MRG - cosv)));
                } else {
                    float nv = (cosv < oS[ni]) ? iE[ni] : 1.0f;
                    negE[ni] += expf(ALPHA * (cosv + MRG) * nv);
                    negV[ni] += nv;
                }
            }
        }
    }
#pragma unroll
    for (int ni = 0; ni < 4; ++ni) {
        float e = negE[ni], v = negV[ni];
        e += __shfl_xor(e, 16); e += __shfl_xor(e, 32);
        v += __shfl_xor(v, 16); v += __shfl_xor(v, 32);
        if (quad == 0) {
            atomicAdd(&negExp[colG[ni]], e);
            atomicAdd(&negVals[colG[ni]], v);
        }
    }
}

// ---------------- finalize: scalar reductions ----------------
__global__ void finalize(const float* __restrict__ posExp, const float* __restrict__ negExp,
                         const float* __restrict__ negVals, const int* __restrict__ cCnt,
                         float* __restrict__ out) {
    float pt = 0.f, nt = 0.f, pws = 0.f, nws = 0.f;
    for (int c = threadIdx.x; c < C_SZ; c += 256) {
        pt += log1pf(posExp[c]);
        nt += log1pf(negExp[c]);
        int cnt = cCnt[c];
        if (cnt > 0) pws += 1.0f;
        int Nc = B_SZ - cnt;
        if (Nc > 0) nws += negVals[c] / (float)Nc;
    }
#pragma unroll
    for (int m = 1; m < 64; m <<= 1) {
        pt += __shfl_xor(pt, m);
        nt += __shfl_xor(nt, m);
        pws += __shfl_xor(pws, m);
        nws += __shfl_xor(nws, m);
    }
    __shared__ float red[4][4];
    int wv = threadIdx.x >> 6;
    if ((threadIdx.x & 63) == 0) {
        red[wv][0] = pt; red[wv][1] = nt; red[wv][2] = pws; red[wv][3] = nws;
    }
    __syncthreads();
    if (threadIdx.x == 0) {
        float PT = 0.f, NT = 0.f, PW = 0.f, NW = 0.f;
        for (int w = 0; w < 4; ++w) {
            PT += red[w][0]; NT += red[w][1]; PW += red[w][2]; NW += red[w][3];
        }
        out[0] = PT / PW + NT / NW;
    }
}

extern "C" void kernel_launch(void* const* d_in, const int* in_sizes, int n_in,
                              void* d_out, int out_size, void* d_ws, size_t ws_size,
                              hipStream_t stream) {
    const float* inputs = (const float*)d_in[0];
    const int* targets = (const int*)d_in[1];
    const float* proxies = (const float*)d_in[2];
    const float* effNum = (const float*)d_in[3];
    const float* lSim = (const float*)d_in[4];
    float* out = (float*)d_out;

    // workspace layout
    bf16* Pbf = (bf16*)d_ws;                        // C*E bf16  (16 MB)
    bf16* Abf = Pbf + (size_t)C_SZ * E_SZ;          // B*E bf16  (1 MB)
    float* oSim = (float*)(Abf + (size_t)B_SZ * E_SZ);
    float* iEff = oSim + C_SZ;
    float* posExp = iEff + C_SZ;
    float* negExp = posExp + C_SZ;
    float* negVals = negExp + C_SZ;
    int* cCnt = (int*)(negVals + C_SZ);

    // zero the accumulator arrays (posExp, negExp, negVals, cCnt contiguous)
    hipMemsetAsync(posExp, 0, (size_t)4 * C_SZ * sizeof(float), stream);

    class_scalars<<<C_SZ / 256, 256, 0, stream>>>(effNum, lSim, oSim, iEff);
    proxy_norm<<<C_SZ / 4, 256, 0, stream>>>(proxies, Pbf);
    convert_inputs<<<(B_SZ * E_SZ) / (256 * 8), 256, 0, stream>>>(inputs, Abf);
    count_targets<<<B_SZ / 256, 256, 0, stream>>>(targets, cCnt);
    gemm_epilogue<<<dim3(C_SZ / 128, B_SZ / 128), 256, 0, stream>>>(
        Abf, Pbf, targets, oSim, iEff, posExp, negExp, negVals);
    finalize<<<1, 256, 0, stream>>>(posExp, negExp, negVals, cCnt, out);
}

// Round 2
// 131.354 us; speedup vs baseline: 1.4481x; 1.4481x over previous
//
#include <hip/hip_runtime.h>
#include <math.h>

#define B_SZ 1024
#define E_SZ 512
#define C_SZ 16384
#define MRG 0.1f
#define ALPHA 32.0f
#define K_HY 1.0f
#define LAM 0.1f

typedef __bf16 bf16;
typedef bf16 bf16x8 __attribute__((ext_vector_type(8)));
typedef float f32x4 __attribute__((ext_vector_type(4)));

__device__ __forceinline__ void async16(const void* g, void* l) {
    __builtin_amdgcn_global_load_lds(
        (const __attribute__((address_space(1))) void*)g,
        (__attribute__((address_space(3))) void*)l,
        16, 0, 0);
}

// ---------------- per-class scalars: outlierSim, invEff ----------------
__global__ void class_scalars(const float* __restrict__ effNum,
                              const float* __restrict__ lSim,
                              float* __restrict__ oSim,
                              float* __restrict__ iEff) {
    int c = blockIdx.x * 256 + threadIdx.x;
    if (c < C_SZ) {
        float en = effNum[c], ls = lSim[c];
        float wb = 1.0f / (1.0f + log1pf(en));
        float eta = (1.0f + K_HY * (1.0f - ls)) * wb + LAM;
        oSim[c] = ls - eta;
        iEff[c] = 1.0f / fmaxf(1.0f, en);
    }
}

// ---------------- proxy row-l2norm -> bf16 (one wave per row) ----------------
__global__ void proxy_norm(const float* __restrict__ proxies, bf16* __restrict__ Pbf) {
    int row = (blockIdx.x * 256 + threadIdx.x) >> 6;
    int lane = threadIdx.x & 63;
    const float* pr = proxies + (size_t)row * E_SZ + lane * 8;
    float4 v0 = *(const float4*)pr;
    float4 v1 = *(const float4*)(pr + 4);
    float ss = v0.x * v0.x + v0.y * v0.y + v0.z * v0.z + v0.w * v0.w +
               v1.x * v1.x + v1.y * v1.y + v1.z * v1.z + v1.w * v1.w;
#pragma unroll
    for (int m = 1; m < 64; m <<= 1) ss += __shfl_xor(ss, m);
    float inv = 1.0f / sqrtf(ss + 1e-12f);
    bf16x8 o;
    o[0] = (bf16)(v0.x * inv); o[1] = (bf16)(v0.y * inv);
    o[2] = (bf16)(v0.z * inv); o[3] = (bf16)(v0.w * inv);
    o[4] = (bf16)(v1.x * inv); o[5] = (bf16)(v1.y * inv);
    o[6] = (bf16)(v1.z * inv); o[7] = (bf16)(v1.w * inv);
    *(bf16x8*)(Pbf + (size_t)row * E_SZ + lane * 8) = o;
}

// ---------------- inputs -> bf16 ----------------
__global__ void convert_inputs(const float* __restrict__ x, bf16* __restrict__ y) {
    int i = (blockIdx.x * 256 + threadIdx.x) * 8;
    float4 v0 = *(const float4*)(x + i);
    float4 v1 = *(const float4*)(x + i + 4);
    bf16x8 o;
    o[0] = (bf16)v0.x; o[1] = (bf16)v0.y; o[2] = (bf16)v0.z; o[3] = (bf16)v0.w;
    o[4] = (bf16)v1.x; o[5] = (bf16)v1.y; o[6] = (bf16)v1.z; o[7] = (bf16)v1.w;
    *(bf16x8*)(y + i) = o;
}

// ---------------- class counts ----------------
__global__ void count_targets(const int* __restrict__ tg, int* __restrict__ cnt) {
    int i = blockIdx.x * 256 + threadIdx.x;
    if (i < B_SZ) atomicAdd(&cnt[tg[i]], 1);
}

// ---------------- fused GEMM (bf16 MFMA) + epilogue ----------------
// Tile: BM=128 (batch rows), BN=128 (classes), BK=32. 4 waves, each 64x64.
__global__ __launch_bounds__(256) void gemm_epilogue(
    const bf16* __restrict__ Abf,   // [B][E]
    const bf16* __restrict__ Pbf,   // [C][E] normalized
    const int* __restrict__ targets,
    const float* __restrict__ oSimA,
    const float* __restrict__ iEffA,
    float* __restrict__ posExp,
    float* __restrict__ negExp,
    float* __restrict__ negVals) {
    __shared__ __align__(16) bf16 Alds[128 * 32];
    __shared__ __align__(16) bf16 Blds[128 * 32];
    __shared__ int tgtLds[128];

    const int tid = threadIdx.x;
    const int wave = tid >> 6, lane = tid & 63;
    const int quad = lane >> 4, l16 = lane & 15;
    const int wRow = (wave >> 1) * 64, wCol = (wave & 1) * 64;
    const int bn0 = blockIdx.x * 128, bm0 = blockIdx.y * 128;

    if (tid < 128) tgtLds[tid] = targets[bm0 + tid];

    f32x4 zero = {0.f, 0.f, 0.f, 0.f};
    f32x4 acc[4][4];
#pragma unroll
    for (int i = 0; i < 4; ++i)
#pragma unroll
        for (int j = 0; j < 4; ++j) acc[i][j] = zero;

    const int ldRow = lane >> 2;      // 0..15 row within 16-row chunk
    const int ldK = (lane & 3) * 8;   // bf16 element offset within BK

    const bf16* gA = Abf + (size_t)(bm0 + wave * 32 + ldRow) * E_SZ + ldK;
    const bf16* gB = Pbf + (size_t)(bn0 + wave * 32 + ldRow) * E_SZ + ldK;

    for (int k0 = 0; k0 < E_SZ; k0 += 32) {
        __syncthreads();
#pragma unroll
        for (int j = 0; j < 2; ++j) {
            int chunk = wave * 2 + j;
            async16(gA + (size_t)j * 16 * E_SZ + k0, &Alds[chunk * 512]);
            async16(gB + (size_t)j * 16 * E_SZ + k0, &Blds[chunk * 512]);
        }
        __syncthreads();
        bf16x8 af[4], bff[4];
#pragma unroll
        for (int mi = 0; mi < 4; ++mi)
            af[mi] = *(const bf16x8*)&Alds[(wRow + mi * 16 + l16) * 32 + quad * 8];
#pragma unroll
        for (int ni = 0; ni < 4; ++ni)
            bff[ni] = *(const bf16x8*)&Blds[(wCol + ni * 16 + l16) * 32 + quad * 8];
#pragma unroll
        for (int mi = 0; mi < 4; ++mi)
#pragma unroll
            for (int ni = 0; ni < 4; ++ni)
                acc[mi][ni] = __builtin_amdgcn_mfma_f32_16x16x32_bf16(
                    af[mi], bff[ni], acc[mi][ni], 0, 0, 0);
    }

    // -------- epilogue: per-class (column) reductions --------
    int colG[4];
    float oS[4], iE[4];
#pragma unroll
    for (int ni = 0; ni < 4; ++ni) {
        colG[ni] = bn0 + wCol + ni * 16 + l16;
        oS[ni] = oSimA[colG[ni]];
        iE[ni] = iEffA[colG[ni]];
    }
    float negE[4] = {0.f, 0.f, 0.f, 0.f};
    float negV[4] = {0.f, 0.f, 0.f, 0.f};
#pragma unroll
    for (int mi = 0; mi < 4; ++mi) {
#pragma unroll
        for (int r = 0; r < 4; ++r) {
            int rowL = wRow + mi * 16 + quad * 4 + r;
            int tgt = tgtLds[rowL];
#pragma unroll
            for (int ni = 0; ni < 4; ++ni) {
                float cosv = acc[mi][ni][r];
                if (tgt == colG[ni]) {
                    // positive position: mask = 1
                    atomicAdd(&posExp[colG[ni]], expf(ALPHA * (MRG - cosv)));
                } else {
                    float nv = (cosv < oS[ni]) ? iE[ni] : 1.0f;
                    negE[ni] += expf(ALPHA * (cosv + MRG) * nv);
                    negV[ni] += nv;
                }
            }
        }
    }
#pragma unroll
    for (int ni = 0; ni < 4; ++ni) {
        float e = negE[ni], v = negV[ni];
        e += __shfl_xor(e, 16); e += __shfl_xor(e, 32);
        v += __shfl_xor(v, 16); v += __shfl_xor(v, 32);
        if (quad == 0) {
            atomicAdd(&negExp[colG[ni]], e);
            atomicAdd(&negVals[colG[ni]], v);
        }
    }
}

// ---------------- finalize stage 1: parallel partial reduction ----------------
// 64 blocks x 256 threads = 16384 lanes -> exactly one class per thread.
__global__ __launch_bounds__(256) void finalize_partial(
    const float* __restrict__ posExp, const float* __restrict__ negExp,
    const float* __restrict__ negVals, const int* __restrict__ cCnt,
    float* __restrict__ acc4) {
    int c = blockIdx.x * 256 + threadIdx.x;
    float pt = log1pf(posExp[c]);
    float nt = log1pf(negExp[c]);
    int cnt = cCnt[c];
    float pws = (cnt > 0) ? 1.0f : 0.0f;
    int Nc = B_SZ - cnt;
    float nws = (Nc > 0) ? negVals[c] / (float)Nc : 0.0f;
#pragma unroll
    for (int m = 1; m < 64; m <<= 1) {
        pt += __shfl_xor(pt, m);
        nt += __shfl_xor(nt, m);
        pws += __shfl_xor(pws, m);
        nws += __shfl_xor(nws, m);
    }
    __shared__ float red[4][4];
    int wv = threadIdx.x >> 6;
    if ((threadIdx.x & 63) == 0) {
        red[wv][0] = pt; red[wv][1] = nt; red[wv][2] = pws; red[wv][3] = nws;
    }
    __syncthreads();
    if (threadIdx.x < 4) {
        float s = red[0][threadIdx.x] + red[1][threadIdx.x] +
                  red[2][threadIdx.x] + red[3][threadIdx.x];
        atomicAdd(&acc4[threadIdx.x], s);
    }
}

// ---------------- finalize stage 2: scalar output ----------------
__global__ void finalize_out(const float* __restrict__ acc4, float* __restrict__ out) {
    out[0] = acc4[0] / acc4[2] + acc4[1] / acc4[3];
}

extern "C" void kernel_launch(void* const* d_in, const int* in_sizes, int n_in,
                              void* d_out, int out_size, void* d_ws, size_t ws_size,
                              hipStream_t stream) {
    const float* inputs = (const float*)d_in[0];
    const int* targets = (const int*)d_in[1];
    const float* proxies = (const float*)d_in[2];
    const float* effNum = (const float*)d_in[3];
    const float* lSim = (const float*)d_in[4];
    float* out = (float*)d_out;

    // workspace layout
    bf16* Pbf = (bf16*)d_ws;                        // C*E bf16  (16 MB)
    bf16* Abf = Pbf + (size_t)C_SZ * E_SZ;          // B*E bf16  (1 MB)
    float* oSim = (float*)(Abf + (size_t)B_SZ * E_SZ);
    float* iEff = oSim + C_SZ;
    float* posExp = iEff + C_SZ;
    float* negExp = posExp + C_SZ;
    float* negVals = negExp + C_SZ;
    int* cCnt = (int*)(negVals + C_SZ);
    float* acc4 = (float*)(cCnt + C_SZ);

    // zero the accumulator arrays (posExp, negExp, negVals, cCnt, acc4 contiguous)
    hipMemsetAsync(posExp, 0, (size_t)4 * C_SZ * sizeof(float) + 4 * sizeof(float), stream);

    class_scalars<<<C_SZ / 256, 256, 0, stream>>>(effNum, lSim, oSim, iEff);
    proxy_norm<<<C_SZ / 4, 256, 0, stream>>>(proxies, Pbf);
    convert_inputs<<<(B_SZ * E_SZ) / (256 * 8), 256, 0, stream>>>(inputs, Abf);
    count_targets<<<B_SZ / 256, 256, 0, stream>>>(targets, cCnt);
    gemm_epilogue<<<dim3(C_SZ / 128, B_SZ / 128), 256, 0, stream>>>(
        Abf, Pbf, targets, oSim, iEff, posExp, negExp, negVals);
    finalize_partial<<<C_SZ / 256, 256, 0, stream>>>(posExp, negExp, negVals, cCnt, acc4);
    finalize_out<<<1, 1, 0, stream>>>(acc4, out);
}